// Round 2
// baseline (31453.210 us; speedup 1.0000x reference)
//
#include <hip/hip_runtime.h>
#include <stdint.h>

// SequentialFeedForward: autoregressive 6-layer MLP, L=2048 steps.
// R2: latency-bound dataflow, 128 persistent blocks x 16 rows.
// h exchanged as 1024 x 8B self-tagged records (tag32|fp16x2) -> poll is
// 4 ulong atomic loads/thread (4x fewer requests than R1); partial-y poll
// done by wave0 only. fp16 weights + fp32 accumulation via v_dot2_f32_f16.

typedef uint32_t u32;
typedef unsigned long long ull;
typedef _Float16 half_t;
typedef _Float16 half2_t __attribute__((ext_vector_type(2)));

#define L_SEQ 2048
#define WIDTH 2048
#define WS    32
#define NAA   21
#define INS   704   // WS*NAA + WS
#define NB    128   // persistent blocks
#define RPB   16    // rows per block
#define RECS  1024  // records per layer (WIDTH/2)

__device__ __forceinline__ float h2f(u32 b){
  union { unsigned short u; half_t h; } c; c.u = (unsigned short)(b & 0xffffu);
  return (float)c.h;
}
__device__ __forceinline__ u32 f2h(float f){
  union { unsigned short u; half_t h; } c; c.h = (half_t)f;
  return (u32)c.u;
}
__device__ __forceinline__ float fdot2f(u32 a, u32 b, float c){
#if __has_builtin(__builtin_amdgcn_fdot2)
  union { u32 u; half2_t v; } ca, cb; ca.u = a; cb.u = b;
  return __builtin_amdgcn_fdot2(ca.v, cb.v, c, false);
#else
  return c + h2f(a)*h2f(b) + h2f(a>>16)*h2f(b>>16);
#endif
}
__device__ __forceinline__ u32 aload(u32* p){
  return __hip_atomic_load(p, __ATOMIC_RELAXED, __HIP_MEMORY_SCOPE_AGENT);
}
__device__ __forceinline__ void astore(u32* p, u32 v){
  __hip_atomic_store(p, v, __ATOMIC_RELAXED, __HIP_MEMORY_SCOPE_AGENT);
}
__device__ __forceinline__ ull aload64(ull* p){
  return __hip_atomic_load(p, __ATOMIC_RELAXED, __HIP_MEMORY_SCOPE_AGENT);
}
__device__ __forceinline__ void astore64(ull* p, ull v){
  __hip_atomic_store(p, v, __ATOMIC_RELAXED, __HIP_MEMORY_SCOPE_AGENT);
}

// ---- pre-pass: transpose W0 (for coalesced c0 gather) ----
__global__ void k_wt(const float* __restrict__ W0, float* __restrict__ W0T){
  int tid = blockIdx.x*256 + threadIdx.x;
  if (tid < INS*WIDTH){
    int c = tid >> 11, i = tid & 2047;
    W0T[(size_t)c*WIDTH + i] = W0[(size_t)i*INS + c];
  }
}

// ---- pre-pass: W1..W4 fp32 -> fp16; Wp[(l*2048+r)*256+j] = cols 8j..8j+7 of row r ----
__global__ void k_wc(const float* __restrict__ A, const float* __restrict__ B,
                     const float* __restrict__ C, const float* __restrict__ D,
                     uint4* __restrict__ Wp){
  int b = blockIdx.x; int l = b >> 11; int r = b & 2047; int j = threadIdx.x;
  const float* S = (l==0)?A:(l==1)?B:(l==2)?C:D;
  const float4* rowp = (const float4*)(S + (size_t)r*WIDTH + 8*j);
  float4 v0 = rowp[0], v1 = rowp[1];
  u32 o0 = f2h(v0.x) | (f2h(v0.y) << 16);
  u32 o1 = f2h(v0.z) | (f2h(v0.w) << 16);
  u32 o2 = f2h(v1.x) | (f2h(v1.y) << 16);
  u32 o3 = f2h(v1.z) | (f2h(v1.w) << 16);
  Wp[(size_t)b*256 + j] = make_uint4(o0,o1,o2,o3);
}

// ---- pre-pass: c0[t][i] = b0[i] + one-hot gather; c0p[t*256+j] = cols 8j..8j+7 ----
__global__ void k_c0(const int* __restrict__ x, const float* __restrict__ W0T,
                     const float* __restrict__ b0, uint4* __restrict__ c0p){
  int t = blockIdx.x, j = threadIdx.x;
  __shared__ int cidx[WS];
  if (j < WS){
    int s = t - (WS-1) + j;
    cidx[j] = (s >= 0) ? (NAA*j + x[s]) : -1;
  }
  __syncthreads();
  float acc[8];
  const float4* bp = (const float4*)(b0 + 8*j);
  float4 b00 = bp[0], b01 = bp[1];
  acc[0]=b00.x; acc[1]=b00.y; acc[2]=b00.z; acc[3]=b00.w;
  acc[4]=b01.x; acc[5]=b01.y; acc[6]=b01.z; acc[7]=b01.w;
  for (int m=0;m<WS;++m){
    int c = cidx[m];
    if (c >= 0){
      const float4* col = (const float4*)(W0T + (size_t)c*WIDTH + 8*j);
      float4 u0 = col[0], u1 = col[1];
      acc[0]+=u0.x; acc[1]+=u0.y; acc[2]+=u0.z; acc[3]+=u0.w;
      acc[4]+=u1.x; acc[5]+=u1.y; acc[6]+=u1.z; acc[7]+=u1.w;
    }
  }
  u32 o[4];
  #pragma unroll
  for (int q=0;q<4;++q) o[q] = f2h(acc[2*q]) | (f2h(acc[2*q+1]) << 16);
  c0p[(size_t)t*256 + j] = make_uint4(o[0],o[1],o[2],o[3]);
}

// ---- pre-pass: reset exchange buffers (every launch: replay-safe) ----
__global__ void k_reset(u32* __restrict__ hb, u32* __restrict__ pb){
  int tid = blockIdx.x*256 + threadIdx.x;
  if (tid < 3*WIDTH) hb[tid] = 0xFFFFFFFFu;   // 3*1024 ulong = 6144 u32
  if (tid < NB)      pb[tid] = 0xFFFFFFFFu;
}

// ---- main persistent dataflow kernel ----
__global__ __launch_bounds__(256, 1) void k_main(
    const float* __restrict__ W0,
    const float* __restrict__ b1, const float* __restrict__ b2,
    const float* __restrict__ b3, const float* __restrict__ b4,
    const float* __restrict__ W5, const float* __restrict__ b5p,
    const uint4* __restrict__ Wp, const uint4* __restrict__ c0p,
    ull* hbq, ull* pbq, u32* pb, float* __restrict__ out)
{
  const int j = threadIdx.x;
  const int X = blockIdx.x;
  const int row16 = RPB*X + (j & 15);

  __shared__ float red[4][RPB];
  __shared__ float ylds;

  // one-time: W0 window weights for h0 cols 8j..8j+7 (fp16 pairs) + col-31 fp32
  u32 w0y[8][16];
  float w31[8];
  #pragma unroll
  for (int e=0;e<8;++e){
    const float4* bp = (const float4*)(W0 + (size_t)(8*j + e)*INS + (INS - WS));
    float arr[32];
    #pragma unroll
    for (int q=0;q<8;++q){
      float4 v = bp[q];
      arr[4*q+0]=v.x; arr[4*q+1]=v.y; arr[4*q+2]=v.z; arr[4*q+3]=v.w;
    }
    #pragma unroll
    for (int p=0;p<16;++p) w0y[e][p] = f2h(arr[2*p]) | (f2h(arr[2*p+1]) << 16);
    w31[e] = arr[31];
  }
  const float w5v = W5[row16];
  const float b5v = b5p[0];
  float bsc[4] = { b1[row16], b2[row16], b3[row16], b4[row16] };

  // sliding y-window (fp16 pairs); slot31 patched in phase A
  u32 yqp[16];
  #pragma unroll
  for (int p=0;p<16;++p) yqp[p] = 0u;
  float u_part[8];
  #pragma unroll
  for (int e=0;e<8;++e) u_part[e] = 0.f;

  uint4 wrow[RPB];
  u32 hh[4];
  const int w = j >> 6;

  auto prefetch = [&](int lw){
    #pragma unroll
    for (int r=0;r<RPB;++r)
      wrow[r] = Wp[((size_t)lw*2048 + RPB*X + r)*256 + j];
  };

  auto doreduce = [&](){
    float accv[RPB];
    #pragma unroll
    for (int r=0;r<RPB;++r){
      float a = 0.f;
      a = fdot2f(wrow[r].x, hh[0], a);
      a = fdot2f(wrow[r].y, hh[1], a);
      a = fdot2f(wrow[r].z, hh[2], a);
      a = fdot2f(wrow[r].w, hh[3], a);
      accv[r] = a;
    }
    // pair-merged butterfly: rows r,r+1 share one 5-level tree
    #pragma unroll
    for (int r=0;r<RPB;r+=2){
      float a = accv[r]   + __shfl_xor(accv[r],   1);
      float b = accv[r+1] + __shfl_xor(accv[r+1], 1);
      float m = (j & 1) ? b : a;
      m += __shfl_xor(m, 2);
      m += __shfl_xor(m, 4);
      m += __shfl_xor(m, 8);
      m += __shfl_xor(m, 16);
      m += __shfl_xor(m, 32);
      if ((j & 63) < 2) red[w][r + (j & 1)] = m;
    }
    __syncthreads();
  };

  auto emit_h = [&](int l, u32 tag, float bias){
    float s = 0.f;
    if (j < 16) s = fmaxf(red[0][j]+red[1][j]+red[2][j]+red[3][j] + bias, 0.f);
    if (j < 64){
      u32 hs = f2h(s);
      u32 lo = __shfl(hs, 2*j);
      u32 hi = __shfl(hs, 2*j + 1);
      if (j < 8)
        astore64(hbq + (size_t)l*RECS + 8*X + j,
                 ((ull)tag << 32) | (ull)(lo | (hi << 16)));
    }
  };

  auto pollh = [&](int l, u32 tag){
    ull* base = hbq + (size_t)l*RECS + 4*j;
    ull r0,r1,r2,r3;
    for(;;){
      r0 = aload64(base+0); r1 = aload64(base+1);
      r2 = aload64(base+2); r3 = aload64(base+3);
      if (((u32)(r0>>32)==tag) & ((u32)(r1>>32)==tag) &
          ((u32)(r2>>32)==tag) & ((u32)(r3>>32)==tag)) break;
    }
    hh[0]=(u32)r0; hh[1]=(u32)r1; hh[2]=(u32)r2; hh[3]=(u32)r3;
  };

  #pragma unroll 1
  for (int t=0; t<L_SEQ; ++t){
    prefetch(0);
    uint4 c0v = c0p[(size_t)t*256 + j];

    // ---- phase A: wave0 polls 128 partials, reduces, broadcasts y[t-1] ----
    if (t > 0){
      if (j < 64){
        u32 lo, hi; ull v;
        const u32 tprev = (u32)(t-1);
        for(;;){
          v = aload64(pbq + j);
          lo = (u32)v; hi = (u32)(v >> 32);
          if (((lo>>16)==tprev) & ((hi>>16)==tprev)) break;
        }
        float p = h2f(lo) + h2f(hi);
        #pragma unroll
        for (int d=1; d<64; d<<=1) p += __shfl_xor(p, d);
        if (j == 0){
          float y = fmaxf(p + b5v, 0.f);
          ylds = y;
          if (X == 0) out[t-1] = y;
        }
      }
    } else {
      if (j == 0) ylds = 0.f;
    }
    __syncthreads();
    float yprev = ylds;
    if (t > 0) yqp[15] |= (f2h(yprev) << 16);

    // h0 cols 8j..8j+7 = relu(c0 + u_part + w31*y[t-1]); pack fp16 pairs
    {
      u32 c0h[4] = { c0v.x, c0v.y, c0v.z, c0v.w };
      float h0v[8];
      #pragma unroll
      for (int e=0;e<8;++e){
        u32 cb = (e & 1) ? (c0h[e>>1] >> 16) : c0h[e>>1];
        h0v[e] = fmaxf(h2f(cb) + u_part[e] + w31[e]*yprev, 0.f);
      }
      #pragma unroll
      for (int q=0;q<4;++q) hh[q] = f2h(h0v[2*q]) | (f2h(h0v[2*q+1]) << 16);
    }

    // ---- layer 1 ----
    doreduce();
    emit_h(0, (u32)t, bsc[0]);
    prefetch(1);
    // off-critical-path: slide window and precompute u_part for step t+1
    {
      #pragma unroll
      for (int p=0;p<15;++p) yqp[p] = (yqp[p] >> 16) | (yqp[p+1] << 16);
      yqp[15] = (yqp[15] >> 16);
      #pragma unroll
      for (int e=0;e<8;++e){
        float a = 0.f;
        #pragma unroll
        for (int p=0;p<16;++p) a = fdot2f(w0y[e][p], yqp[p], a);
        u_part[e] = a;
      }
    }
    pollh(0, (u32)t);

    // ---- layer 2 ----
    doreduce();
    emit_h(1, (u32)t, bsc[1]);
    prefetch(2);
    pollh(1, (u32)t);

    // ---- layer 3 ----
    doreduce();
    emit_h(2, (u32)t, bsc[2]);
    prefetch(3);
    pollh(2, (u32)t);

    // ---- layer 4 + W5 partial (h4 never exchanged) ----
    doreduce();
    if (j < 16){
      float s = fmaxf(red[0][j]+red[1][j]+red[2][j]+red[3][j] + bsc[3], 0.f);
      float pp = s * w5v;
      pp += __shfl_xor(pp, 1);
      pp += __shfl_xor(pp, 2);
      pp += __shfl_xor(pp, 4);
      pp += __shfl_xor(pp, 8);
      if (j == 0) astore(&pb[X], ((u32)t << 16) | f2h(pp));
    }
    // red[] reuse ordered by the phase-A __syncthreads of iteration t+1
  }

  // epilogue: y[L-1]
  if (X == 0 && j < 64){
    u32 lo, hi; ull v;
    const u32 tl = (u32)(L_SEQ-1);
    for(;;){
      v = aload64(pbq + j);
      lo = (u32)v; hi = (u32)(v >> 32);
      if (((lo>>16)==tl) & ((hi>>16)==tl)) break;
    }
    float p = h2f(lo) + h2f(hi);
    #pragma unroll
    for (int d=1; d<64; d<<=1) p += __shfl_xor(p, d);
    if (j == 0) out[L_SEQ-1] = fmaxf(p + b5v, 0.f);
  }
}

extern "C" void kernel_launch(void* const* d_in, const int* in_sizes, int n_in,
                              void* d_out, int out_size, void* d_ws, size_t ws_size,
                              hipStream_t stream) {
  (void)in_sizes; (void)n_in; (void)out_size; (void)ws_size;
  const int*   x  = (const int*)  d_in[0];
  const float* W0 = (const float*)d_in[1];
  const float* b0 = (const float*)d_in[2];
  const float* W1 = (const float*)d_in[3];
  const float* b1 = (const float*)d_in[4];
  const float* W2 = (const float*)d_in[5];
  const float* b2 = (const float*)d_in[6];
  const float* W3 = (const float*)d_in[7];
  const float* b3 = (const float*)d_in[8];
  const float* W4 = (const float*)d_in[9];
  const float* b4 = (const float*)d_in[10];
  const float* W5 = (const float*)d_in[11];
  const float* b5 = (const float*)d_in[12];
  float* out = (float*)d_out;
  char*  ws  = (char*)d_ws;

  // ws layout (16B-aligned), total ~47.7 MB
  constexpr size_t OFF_WP  = 0;                       // 4*2048*256*16 = 33,554,432
  constexpr size_t OFF_C0  = 33554432;                // 2048*256*16   =  8,388,608
  constexpr size_t OFF_W0T = 41943040;                // 704*2048*4    =  5,767,168
  constexpr size_t OFF_HB  = 47710208;                // 3*1024*8      =     24,576
  constexpr size_t OFF_PB  = 47734784;                // 128*4         =       512

  uint4* Wp  = (uint4*)(ws + OFF_WP);
  uint4* c0p = (uint4*)(ws + OFF_C0);
  float* W0T = (float*)(ws + OFF_W0T);
  u32*   hb  = (u32*)  (ws + OFF_HB);
  ull*   hbq = (ull*)  (ws + OFF_HB);
  u32*   pb  = (u32*)  (ws + OFF_PB);
  ull*   pbq = (ull*)  (ws + OFF_PB);

  k_wt   <<<5632, 256, 0, stream>>>(W0, W0T);
  k_wc   <<<8192, 256, 0, stream>>>(W1, W2, W3, W4, Wp);
  k_c0   <<<2048, 256, 0, stream>>>(x, W0T, b0, c0p);
  k_reset<<<24,   256, 0, stream>>>(hb, pb);
  k_main <<<NB,   256, 0, stream>>>(W0, b1, b2, b3, b4, W5, b5,
                                    Wp, c0p, hbq, pbq, pb, out);
}

// Round 3
// 29722.519 us; speedup vs baseline: 1.0582x; 1.0582x over previous
//
#include <hip/hip_runtime.h>
#include <stdint.h>

// SequentialFeedForward: autoregressive 6-layer MLP, L=2048 steps.
// R3: 256 persistent blocks x 8 rows (R1 skeleton) with:
//  - transposed record layout rec[k*256+j]: polls are 4 fully-coalesced
//    8B-lane loads; record == exactly the data the thread consumes
//  - all dense weights register-resident (no per-step weight loads)
//  - 2-deep pipelined polls (two load sets in flight)
//  - pair-merged butterflies, double-buffered LDS reduce buffer

typedef uint32_t u32;
typedef unsigned long long ull;
typedef _Float16 half_t;
typedef _Float16 half2_t __attribute__((ext_vector_type(2)));

#define L_SEQ 2048
#define WIDTH 2048
#define WS    32
#define NAA   21
#define INS   704   // WS*NAA + WS
#define NB    256   // persistent blocks
#define RECS  1024  // records per layer (WIDTH/2)

__device__ __forceinline__ float h2f(u32 b){
  union { unsigned short u; half_t h; } c; c.u = (unsigned short)(b & 0xffffu);
  return (float)c.h;
}
__device__ __forceinline__ u32 f2h(float f){
  union { unsigned short u; half_t h; } c; c.h = (half_t)f;
  return (u32)c.u;
}
__device__ __forceinline__ float fdot2f(u32 a, u32 b, float c){
#if __has_builtin(__builtin_amdgcn_fdot2)
  union { u32 u; half2_t v; } ca, cb; ca.u = a; cb.u = b;
  return __builtin_amdgcn_fdot2(ca.v, cb.v, c, false);
#else
  return c + h2f(a)*h2f(b) + h2f(a>>16)*h2f(b>>16);
#endif
}
__device__ __forceinline__ u32 aload(u32* p){
  return __hip_atomic_load(p, __ATOMIC_RELAXED, __HIP_MEMORY_SCOPE_AGENT);
}
__device__ __forceinline__ void astore(u32* p, u32 v){
  __hip_atomic_store(p, v, __ATOMIC_RELAXED, __HIP_MEMORY_SCOPE_AGENT);
}
__device__ __forceinline__ ull aload64(ull* p){
  return __hip_atomic_load(p, __ATOMIC_RELAXED, __HIP_MEMORY_SCOPE_AGENT);
}
__device__ __forceinline__ void astore64(ull* p, ull v){
  __hip_atomic_store(p, v, __ATOMIC_RELAXED, __HIP_MEMORY_SCOPE_AGENT);
}

// ---- pre-pass: transpose W0 (for coalesced c0 gather) ----
__global__ void k_wt(const float* __restrict__ W0, float* __restrict__ W0T){
  int tid = blockIdx.x*256 + threadIdx.x;
  if (tid < INS*WIDTH){
    int c = tid >> 11, i = tid & 2047;
    W0T[(size_t)c*WIDTH + i] = W0[(size_t)i*INS + c];
  }
}

// ---- pre-pass: W1..W4 fp32 -> fp16 ----
// Wp[(l*2048+r)*256 + j] uint4: component k = half2(W[r][512k+2j], W[r][512k+2j+1])
__global__ void k_wc(const float* __restrict__ A, const float* __restrict__ B,
                     const float* __restrict__ C, const float* __restrict__ D,
                     uint4* __restrict__ Wp){
  int b = blockIdx.x; int l = b >> 11; int r = b & 2047; int j = threadIdx.x;
  const float* S = (l==0)?A:(l==1)?B:(l==2)?C:D;
  const float2* p2 = (const float2*)(S + (size_t)r*WIDTH);
  u32 o[4];
  #pragma unroll
  for (int k=0;k<4;++k){
    float2 v = p2[256*k + j];
    o[k] = f2h(v.x) | (f2h(v.y) << 16);
  }
  Wp[(size_t)b*256 + j] = make_uint4(o[0],o[1],o[2],o[3]);
}

// ---- pre-pass: c0[t][i] = b0[i] + one-hot gather ----
// c0p[t*256+j] uint4: component k = half2(c0[512k+2j], c0[512k+2j+1])
__global__ void k_c0(const int* __restrict__ x, const float* __restrict__ W0T,
                     const float* __restrict__ b0, uint4* __restrict__ c0p){
  int t = blockIdx.x, j = threadIdx.x;
  __shared__ int cidx[WS];
  if (j < WS){
    int s = t - (WS-1) + j;
    cidx[j] = (s >= 0) ? (NAA*j + x[s]) : -1;
  }
  __syncthreads();
  float ax[4], ay[4];
  const float2* b2p = (const float2*)b0;
  #pragma unroll
  for (int k=0;k<4;++k){ float2 v = b2p[256*k + j]; ax[k]=v.x; ay[k]=v.y; }
  for (int m=0;m<WS;++m){
    int c = cidx[m];
    if (c >= 0){
      const float2* w2 = (const float2*)(W0T + (size_t)c*WIDTH);
      #pragma unroll
      for (int k=0;k<4;++k){ float2 v = w2[256*k + j]; ax[k]+=v.x; ay[k]+=v.y; }
    }
  }
  u32 o[4];
  #pragma unroll
  for (int k=0;k<4;++k) o[k] = f2h(ax[k]) | (f2h(ay[k]) << 16);
  c0p[(size_t)t*256 + j] = make_uint4(o[0],o[1],o[2],o[3]);
}

// ---- pre-pass: reset exchange buffers (every launch: replay-safe) ----
__global__ void k_reset(u32* __restrict__ hb, u32* __restrict__ pb){
  int tid = blockIdx.x*256 + threadIdx.x;
  if (tid < 3*WIDTH) hb[tid] = 0xFFFFFFFFu;   // 3*1024 ull = 6144 u32
  if (tid < NB)      pb[tid] = 0xFFFFFFFFu;
}

// ---- main persistent dataflow kernel ----
__global__ __launch_bounds__(256, 1) void k_main(
    const float* __restrict__ W0,
    const float* __restrict__ b1, const float* __restrict__ b2,
    const float* __restrict__ b3, const float* __restrict__ b4,
    const float* __restrict__ W5, const float* __restrict__ b5p,
    const uint4* __restrict__ Wp, const uint4* __restrict__ c0p,
    ull* hbq, u32* pb, float* __restrict__ out)
{
  const int j  = threadIdx.x;
  const int X  = blockIdx.x;
  const int r8 = j & 7;
  const int row = 8*X + r8;

  __shared__ float red[2][4][8];   // double-buffered cross-wave reduce
  __shared__ float redp[4];

  // ---- one-time: all 4 dense layers' rows register-resident ----
  uint4 wreg[4][8];
  #pragma unroll
  for (int l=0;l<4;++l)
    #pragma unroll
    for (int r=0;r<8;++r)
      wreg[l][r] = Wp[((size_t)l*2048 + 8*X + r)*256 + j];

  // ---- one-time: W0 window weights for this thread's 8 h0-columns ----
  // e = 2k+s -> h0 col 512k+2j+s
  u32 w0y[8][16];
  float w31[8];
  #pragma unroll
  for (int k=0;k<4;++k)
    #pragma unroll
    for (int s=0;s<2;++s){
      int e = 2*k+s;
      int rr = 512*k + 2*j + s;
      const float4* bp = (const float4*)(W0 + (size_t)rr*INS + (INS - WS));
      float arr[32];
      #pragma unroll
      for (int q=0;q<8;++q){
        float4 v = bp[q];
        arr[4*q+0]=v.x; arr[4*q+1]=v.y; arr[4*q+2]=v.z; arr[4*q+3]=v.w;
      }
      #pragma unroll
      for (int p=0;p<16;++p) w0y[e][p] = f2h(arr[2*p]) | (f2h(arr[2*p+1]) << 16);
      w31[e] = arr[31];
    }
  const float w5v = W5[row];
  const float b5v = b5p[0];
  float bsc[4] = { b1[row], b2[row], b3[row], b4[row] };

  // sliding y-window (fp16 pairs); slot 31 patched in phase A
  u32 yqp[16];
  #pragma unroll
  for (int p=0;p<16;++p) yqp[p] = 0u;
  float u_part[8];
  #pragma unroll
  for (int e=0;e<8;++e) u_part[e] = 0.f;

  u32 hh[4];
  const int w = j >> 6;

  auto doreduce = [&](const uint4 (&wr)[8], int buf){
    float accv[8];
    #pragma unroll
    for (int r=0;r<8;++r){
      float a = 0.f;
      a = fdot2f(wr[r].x, hh[0], a);
      a = fdot2f(wr[r].y, hh[1], a);
      a = fdot2f(wr[r].z, hh[2], a);
      a = fdot2f(wr[r].w, hh[3], a);
      accv[r] = a;
    }
    #pragma unroll
    for (int r=0;r<8;r+=2){
      float a = accv[r]   + __shfl_xor(accv[r],   1);
      float b = accv[r+1] + __shfl_xor(accv[r+1], 1);
      float m = (j & 1) ? b : a;
      m += __shfl_xor(m, 2);
      m += __shfl_xor(m, 4);
      m += __shfl_xor(m, 8);
      m += __shfl_xor(m, 16);
      m += __shfl_xor(m, 32);
      if ((j & 63) < 2) red[buf][w][r + (j & 1)] = m;
    }
    __syncthreads();
  };

  // emit: rows 8X..8X+7 -> 4 records at rec[(X>>6)*256 + 4*(X&63) + m]
  auto emit_h = [&](int l, u32 tag, float bias, int buf){
    float s = 0.f;
    if (j < 8)
      s = fmaxf(red[buf][0][j]+red[buf][1][j]+red[buf][2][j]+red[buf][3][j] + bias, 0.f);
    if (j < 64){
      u32 hs = f2h(s);
      u32 lo = __shfl(hs, 2*(j & 3));
      u32 hi = __shfl(hs, 2*(j & 3) + 1);
      if (j < 4)
        astore64(hbq + (size_t)l*RECS + (X>>6)*256 + 4*(X&63) + j,
                 ((ull)tag << 32) | (ull)(lo | (hi << 16)));
    }
  };

  // poll: 4 coalesced 8B loads (rec[k*256+j]), 2 sets in flight
  auto pollh = [&](int l, u32 tag){
    ull* base = hbq + (size_t)l*RECS;
    ull A0,A1,A2,A3,B0,B1,B2,B3;
    A0=aload64(base+     j); A1=aload64(base+ 256+j);
    A2=aload64(base+ 512+j); A3=aload64(base+ 768+j);
    B0=aload64(base+     j); B1=aload64(base+ 256+j);
    B2=aload64(base+ 512+j); B3=aload64(base+ 768+j);
    for(;;){
      if (((u32)(A0>>32)==tag) & ((u32)(A1>>32)==tag) &
          ((u32)(A2>>32)==tag) & ((u32)(A3>>32)==tag)) break;
      A0=B0; A1=B1; A2=B2; A3=B3;
      B0=aload64(base+     j); B1=aload64(base+ 256+j);
      B2=aload64(base+ 512+j); B3=aload64(base+ 768+j);
    }
    hh[0]=(u32)A0; hh[1]=(u32)A1; hh[2]=(u32)A2; hh[3]=(u32)A3;
  };

  #pragma unroll 1
  for (int t=0; t<L_SEQ; ++t){
    uint4 c0v = c0p[(size_t)t*256 + j];   // prefetch (used in h0)

    // ---- phase A: all threads poll pb[j] (coalesced), reduce y[t-1] ----
    float yprev = 0.f;
    if (t > 0){
      const u32 tprev = (u32)(t-1);
      u32 A = aload(&pb[j]);
      u32 B = aload(&pb[j]);
      for(;;){
        if ((A >> 16) == tprev) break;
        A = B;
        B = aload(&pb[j]);
      }
      float p = h2f(A);
      #pragma unroll
      for (int d=1; d<64; d<<=1) p += __shfl_xor(p, d);
      if ((j & 63) == 0) redp[w] = p;
      __syncthreads();
      float y = fmaxf(redp[0]+redp[1]+redp[2]+redp[3] + b5v, 0.f);
      if (X == 0 && j == 0) out[t-1] = y;
      yprev = y;
      yqp[15] |= (f2h(y) << 16);
    }

    // h0 cols (512k+2j+s) = relu(c0 + u_part + w31*y[t-1]); pack fp16 pairs
    {
      u32 c0h[4] = { c0v.x, c0v.y, c0v.z, c0v.w };
      #pragma unroll
      for (int k=0;k<4;++k){
        float h0a = fmaxf(h2f(c0h[k])       + u_part[2*k]   + w31[2*k]*yprev,   0.f);
        float h0b = fmaxf(h2f(c0h[k] >> 16) + u_part[2*k+1] + w31[2*k+1]*yprev, 0.f);
        hh[k] = f2h(h0a) | (f2h(h0b) << 16);
      }
    }

    // ---- layer 1 ----
    doreduce(wreg[0], 0);
    emit_h(0, (u32)t, bsc[0], 0);
    // off-critical-path: slide window, precompute u_part for step t+1
    {
      #pragma unroll
      for (int p=0;p<15;++p) yqp[p] = (yqp[p] >> 16) | (yqp[p+1] << 16);
      yqp[15] = (yqp[15] >> 16);
      #pragma unroll
      for (int e=0;e<8;++e){
        float a = 0.f;
        #pragma unroll
        for (int p=0;p<16;++p) a = fdot2f(w0y[e][p], yqp[p], a);
        u_part[e] = a;
      }
    }
    pollh(0, (u32)t);

    // ---- layer 2 ----
    doreduce(wreg[1], 1);
    emit_h(1, (u32)t, bsc[1], 1);
    pollh(1, (u32)t);

    // ---- layer 3 ----
    doreduce(wreg[2], 0);
    emit_h(2, (u32)t, bsc[2], 0);
    pollh(2, (u32)t);

    // ---- layer 4 + W5 partial (h4 never exchanged) ----
    doreduce(wreg[3], 1);
    {
      float s = 0.f;
      if (j < 8)
        s = fmaxf(red[1][0][j]+red[1][1][j]+red[1][2][j]+red[1][3][j] + bsc[3], 0.f);
      if (j < 64){
        float pp = s * w5v;
        pp += __shfl_xor(pp, 1);
        pp += __shfl_xor(pp, 2);
        pp += __shfl_xor(pp, 4);
        if (j == 0) astore(&pb[X], ((u32)t << 16) | f2h(pp));
      }
    }
    // red[] reuse ordered by phase-A __syncthreads + double buffering
  }

  // epilogue: y[L-1]
  if (X == 0){
    const u32 tl = (u32)(L_SEQ-1);
    u32 A = aload(&pb[j]);
    for(;;){
      if ((A >> 16) == tl) break;
      A = aload(&pb[j]);
    }
    float p = h2f(A);
    #pragma unroll
    for (int d=1; d<64; d<<=1) p += __shfl_xor(p, d);
    if ((j & 63) == 0) redp[w] = p;
    __syncthreads();
    if (j == 0) out[L_SEQ-1] = fmaxf(redp[0]+redp[1]+redp[2]+redp[3] + b5v, 0.f);
  }
}

extern "C" void kernel_launch(void* const* d_in, const int* in_sizes, int n_in,
                              void* d_out, int out_size, void* d_ws, size_t ws_size,
                              hipStream_t stream) {
  (void)in_sizes; (void)n_in; (void)out_size; (void)ws_size;
  const int*   x  = (const int*)  d_in[0];
  const float* W0 = (const float*)d_in[1];
  const float* b0 = (const float*)d_in[2];
  const float* W1 = (const float*)d_in[3];
  const float* b1 = (const float*)d_in[4];
  const float* W2 = (const float*)d_in[5];
  const float* b2 = (const float*)d_in[6];
  const float* W3 = (const float*)d_in[7];
  const float* b3 = (const float*)d_in[8];
  const float* W4 = (const float*)d_in[9];
  const float* b4 = (const float*)d_in[10];
  const float* W5 = (const float*)d_in[11];
  const float* b5 = (const float*)d_in[12];
  float* out = (float*)d_out;
  char*  ws  = (char*)d_ws;

  // ws layout (16B-aligned), total ~47.7 MB
  constexpr size_t OFF_WP  = 0;                       // 4*2048*256*16 = 33,554,432
  constexpr size_t OFF_C0  = 33554432;                // 2048*256*16   =  8,388,608
  constexpr size_t OFF_W0T = 41943040;                // 704*2048*4    =  5,767,168
  constexpr size_t OFF_HB  = 47710208;                // 3*1024*8     =      24,576
  constexpr size_t OFF_PB  = 47734784;                // 256*4        =       1,024

  uint4* Wp  = (uint4*)(ws + OFF_WP);
  uint4* c0p = (uint4*)(ws + OFF_C0);
  float* W0T = (float*)(ws + OFF_W0T);
  u32*   hb  = (u32*)  (ws + OFF_HB);
  ull*   hbq = (ull*)  (ws + OFF_HB);
  u32*   pb  = (u32*)  (ws + OFF_PB);

  k_wt   <<<5632, 256, 0, stream>>>(W0, W0T);
  k_wc   <<<8192, 256, 0, stream>>>(W1, W2, W3, W4, Wp);
  k_c0   <<<2048, 256, 0, stream>>>(x, W0T, b0, c0p);
  k_reset<<<24,   256, 0, stream>>>(hb, pb);
  k_main <<<NB,   256, 0, stream>>>(W0, b1, b2, b3, b4, W5, b5,
                                    Wp, c0p, hbq, pb, out);
}

// Round 4
// 20084.549 us; speedup vs baseline: 1.5660x; 1.4799x over previous
//
#include <hip/hip_runtime.h>
#include <stdint.h>

// SequentialFeedForward: autoregressive 6-layer MLP, L=2048 steps.
// R4: stage-partitioned dataflow. 4 groups x 64 blocks; group g computes
// layer g+1 (32 rows/block). Each group polls ONLY its input buffer
// (tagged u32 records, tag16|fp16), sleeps through its idle window
// (s_sleep issues no fabric traffic). G0 folds y-reduction (W5 dot of G3's
// h4 records), h0 window logic, and out[] writes. 4 hops/step.

typedef uint32_t u32;
typedef _Float16 half_t;
typedef _Float16 half2_t __attribute__((ext_vector_type(2)));

#define L_SEQ 2048
#define WIDTH 2048
#define WS    32
#define NAA   21
#define INS   704   // WS*NAA + WS
#define NB    256
#define GSZ   64    // blocks per stage group
#define SLP_FAIL 2  // ~128 cy per failed poll sweep
#define SLP_IDLE 20 // ~0.53 us per unit
#define N_IDLE   3  // idle sleeps after emit (~1.6 us)

__device__ __forceinline__ float h2f(u32 b){
  union { unsigned short u; half_t h; } c; c.u = (unsigned short)(b & 0xffffu);
  return (float)c.h;
}
__device__ __forceinline__ u32 f2h(float f){
  union { unsigned short u; half_t h; } c; c.h = (half_t)f;
  return (u32)c.u;
}
__device__ __forceinline__ float fdot2f(u32 a, u32 b, float c){
#if __has_builtin(__builtin_amdgcn_fdot2)
  union { u32 u; half2_t v; } ca, cb; ca.u = a; cb.u = b;
  return __builtin_amdgcn_fdot2(ca.v, cb.v, c, false);
#else
  return c + h2f(a)*h2f(b) + h2f(a>>16)*h2f(b>>16);
#endif
}
__device__ __forceinline__ u32 aload(u32* p){
  return __hip_atomic_load(p, __ATOMIC_RELAXED, __HIP_MEMORY_SCOPE_AGENT);
}
__device__ __forceinline__ void astore(u32* p, u32 v){
  __hip_atomic_store(p, v, __ATOMIC_RELAXED, __HIP_MEMORY_SCOPE_AGENT);
}

// ---- pre-pass: transpose W0 (for coalesced c0 gather) ----
__global__ void k_wt(const float* __restrict__ W0, float* __restrict__ W0T){
  int tid = blockIdx.x*256 + threadIdx.x;
  if (tid < INS*WIDTH){
    int c = tid >> 11, i = tid & 2047;
    W0T[(size_t)c*WIDTH + i] = W0[(size_t)i*INS + c];
  }
}

// ---- pre-pass: W1..W4 fp32 -> fp16 ----
// Wp[(l*2048+r)*256 + j] uint4: comp q = half2(W[r][256*(2q)+j], W[r][256*(2q+1)+j])
__global__ void k_wc(const float* __restrict__ A, const float* __restrict__ B,
                     const float* __restrict__ C, const float* __restrict__ D,
                     uint4* __restrict__ Wp){
  int b = blockIdx.x; int l = b >> 11; int r = b & 2047; int j = threadIdx.x;
  const float* S = (l==0)?A:(l==1)?B:(l==2)?C:D;
  const float* row = S + (size_t)r*WIDTH;
  u32 o[4];
  #pragma unroll
  for (int q=0;q<4;++q)
    o[q] = f2h(row[256*(2*q)+j]) | (f2h(row[256*(2*q+1)+j]) << 16);
  Wp[(size_t)b*256 + j] = make_uint4(o[0],o[1],o[2],o[3]);
}

// ---- pre-pass: c0[t][col] = b0 + one-hot gather; thread j owns cols {256k+j} ----
__global__ void k_c0(const int* __restrict__ x, const float* __restrict__ W0T,
                     const float* __restrict__ b0, uint4* __restrict__ c0p){
  int t = blockIdx.x, j = threadIdx.x;
  __shared__ int cidx[WS];
  if (j < WS){
    int s = t - (WS-1) + j;
    cidx[j] = (s >= 0) ? (NAA*j + x[s]) : -1;
  }
  __syncthreads();
  float acc[8];
  #pragma unroll
  for (int k=0;k<8;++k) acc[k] = b0[256*k + j];
  for (int m=0;m<WS;++m){
    int c = cidx[m];
    if (c >= 0){
      const float* col = W0T + (size_t)c*WIDTH;
      #pragma unroll
      for (int k=0;k<8;++k) acc[k] += col[256*k + j];
    }
  }
  u32 o[4];
  #pragma unroll
  for (int q=0;q<4;++q) o[q] = f2h(acc[2*q]) | (f2h(acc[2*q+1]) << 16);
  c0p[(size_t)t*256 + j] = make_uint4(o[0],o[1],o[2],o[3]);
}

// ---- pre-pass: window weights, packed for G0's idle-window streaming ----
// wyb[(16k+p)*256 + j] = half2(W0[256k+j][672+2p], W0[256k+j][673+2p])
__global__ void k_wy(const float* __restrict__ W0, u32* __restrict__ wyb){
  int b = blockIdx.x; int k = b >> 4, p = b & 15; int j = threadIdx.x;
  int col = 256*k + j;
  float a = W0[(size_t)col*INS + (INS-WS) + 2*p];
  float c = W0[(size_t)col*INS + (INS-WS) + 2*p + 1];
  wyb[(size_t)b*256 + j] = f2h(a) | (f2h(c) << 16);
}

// ---- pre-pass: reset exchange buffers (every launch: replay-safe) ----
__global__ void k_reset(u32* __restrict__ hb){
  int tid = blockIdx.x*256 + threadIdx.x;
  if (tid < 4*WIDTH) hb[tid] = 0xFFFFFFFFu;
}

// ---- main persistent dataflow kernel ----
__global__ __launch_bounds__(256, 1) void k_main(
    const float* __restrict__ W0,
    const float* __restrict__ b1, const float* __restrict__ b2,
    const float* __restrict__ b3, const float* __restrict__ b4,
    const float* __restrict__ W5, const float* __restrict__ b5p,
    const uint4* __restrict__ Wp, const uint4* __restrict__ c0p,
    const u32* __restrict__ wyb,
    u32* hb, float* __restrict__ out)
{
  const int j  = threadIdx.x;
  const int X  = blockIdx.x;
  const int g  = X >> 6;      // stage group 0..3
  const int Xl = X & 63;      // block within group
  const int lw = j & 63;
  const int w  = j >> 6;

  __shared__ float red[4][32];
  __shared__ float redp[4];

  // stage weight slice: rows 32*Xl .. 32*Xl+31 of W_{g+1}
  uint4 wreg[32];
  #pragma unroll
  for (int r=0;r<32;++r)
    wreg[r] = Wp[((size_t)g*2048 + 32*Xl + r)*256 + j];

  const float* bp = (g==0)?b1:(g==1)?b2:(g==2)?b3:b4;
  float bv = 0.f;
  if (j < 32) bv = bp[32*Xl + j];

  u32 hh[4];

  // dot(32 rows) + 6-level merged butterfly + cross-wave sum + tagged emit
  auto doreduce_emit = [&](u32 tag){
    float c32[32];
    #pragma unroll
    for (int r=0;r<32;++r){
      float a = 0.f;
      a = fdot2f(wreg[r].x, hh[0], a);
      a = fdot2f(wreg[r].y, hh[1], a);
      a = fdot2f(wreg[r].z, hh[2], a);
      a = fdot2f(wreg[r].w, hh[3], a);
      c32[r] = a;
    }
    float c16[16];
    #pragma unroll
    for (int i=0;i<16;++i){
      float v = c32[2*i]   + __shfl_xor(c32[2*i],   1);
      float u = c32[2*i+1] + __shfl_xor(c32[2*i+1], 1);
      c16[i] = (lw & 1) ? u : v;
    }
    float c8[8];
    #pragma unroll
    for (int i=0;i<8;++i){
      float v = c16[2*i]   + __shfl_xor(c16[2*i],   2);
      float u = c16[2*i+1] + __shfl_xor(c16[2*i+1], 2);
      c8[i] = (lw & 2) ? u : v;
    }
    float c4[4];
    #pragma unroll
    for (int i=0;i<4;++i){
      float v = c8[2*i]   + __shfl_xor(c8[2*i],   4);
      float u = c8[2*i+1] + __shfl_xor(c8[2*i+1], 4);
      c4[i] = (lw & 4) ? u : v;
    }
    float c2[2];
    #pragma unroll
    for (int i=0;i<2;++i){
      float v = c4[2*i]   + __shfl_xor(c4[2*i],   8);
      float u = c4[2*i+1] + __shfl_xor(c4[2*i+1], 8);
      c2[i] = (lw & 8) ? u : v;
    }
    float v1 = c2[0] + __shfl_xor(c2[0], 16);
    float u1 = c2[1] + __shfl_xor(c2[1], 16);
    float c1 = (lw & 16) ? u1 : v1;
    float tot = c1 + __shfl_xor(c1, 32);
    if (lw < 32) red[w][lw] = tot;   // row = lw (bits 0..4 selected above)
    __syncthreads();
    if (j < 32){
      float s = fmaxf(red[0][j]+red[1][j]+red[2][j]+red[3][j] + bv, 0.f);
      astore(&hb[(size_t)g*WIDTH + 32*Xl + j], (tag << 16) | f2h(s));
    }
    __syncthreads();
  };

  // poll input buffer gin for tag; payload lands directly in hh
  auto pollh = [&](int gin, u32 tag){
    u32 rec[8];
    u32* base = hb + (size_t)gin*WIDTH;
    for(;;){
      #pragma unroll
      for (int k=0;k<8;++k) rec[k] = aload(base + 256*k + j);
      bool ok = true;
      #pragma unroll
      for (int k=0;k<8;++k) ok &= ((rec[k] >> 16) == tag);
      if (ok) break;
      __builtin_amdgcn_s_sleep(SLP_FAIL);
    }
    #pragma unroll
    for (int q=0;q<4;++q) hh[q] = (rec[2*q] & 0xffffu) | (rec[2*q+1] << 16);
  };

  // stagger pipeline-fill polling
  for (int i=0;i<g;++i) __builtin_amdgcn_s_sleep(SLP_IDLE);

  if (g > 0){
    const int gin = g - 1;
    #pragma unroll 1
    for (int t=0; t<L_SEQ; ++t){
      pollh(gin, (u32)t);
      doreduce_emit((u32)t);
      for (int i=0;i<N_IDLE;++i) __builtin_amdgcn_s_sleep(SLP_IDLE);
    }
  } else {
    // ---- G0: y-reduction + h0 + layer 1 ----
    float w5f[8], w31v[8];
    #pragma unroll
    for (int k=0;k<8;++k){
      w5f[k]  = W5[256*k + j];
      w31v[k] = W0[(size_t)(256*k + j)*INS + (INS-1)];
    }
    const float b5v = b5p[0];
    u32 yqp[16];
    #pragma unroll
    for (int p=0;p<16;++p) yqp[p] = 0u;
    float u_part[8];
    #pragma unroll
    for (int k=0;k<8;++k) u_part[k] = 0.f;

    #pragma unroll 1
    for (int t=0; t<L_SEQ; ++t){
      float y = 0.f;
      if (t > 0){
        // poll h4 records (tag t-1), dot with W5, block-reduce -> y[t-1]
        u32 rec[8];
        u32* base = hb + (size_t)3*WIDTH;
        const u32 tag = (u32)(t-1);
        for(;;){
          #pragma unroll
          for (int k=0;k<8;++k) rec[k] = aload(base + 256*k + j);
          bool ok = true;
          #pragma unroll
          for (int k=0;k<8;++k) ok &= ((rec[k] >> 16) == tag);
          if (ok) break;
          __builtin_amdgcn_s_sleep(SLP_FAIL);
        }
        float yp = 0.f;
        #pragma unroll
        for (int k=0;k<8;++k) yp += w5f[k] * h2f(rec[k]);
        #pragma unroll
        for (int d=1; d<64; d<<=1) yp += __shfl_xor(yp, d);
        if (lw == 0) redp[w] = yp;
        __syncthreads();
        y = fmaxf(redp[0]+redp[1]+redp[2]+redp[3] + b5v, 0.f);
        if (X == 0 && j == 0) out[t-1] = y;
        yqp[15] |= (f2h(y) << 16);
      }
      uint4 c0v = c0p[(size_t)t*256 + j];
      // h0 cols {256k+j} = relu(c0 + u_part + w31*y)
      {
        u32 c0h[4] = { c0v.x, c0v.y, c0v.z, c0v.w };
        float h0v[8];
        #pragma unroll
        for (int q=0;q<4;++q){
          h0v[2*q]   = fmaxf(h2f(c0h[q])       + u_part[2*q]   + w31v[2*q]*y,   0.f);
          h0v[2*q+1] = fmaxf(h2f(c0h[q] >> 16) + u_part[2*q+1] + w31v[2*q+1]*y, 0.f);
        }
        #pragma unroll
        for (int q=0;q<4;++q) hh[q] = f2h(h0v[2*q]) | (f2h(h0v[2*q+1]) << 16);
      }
      doreduce_emit((u32)t);
      // idle window: slide y-window, stream window weights, precompute u_part
      {
        #pragma unroll
        for (int p=0;p<15;++p) yqp[p] = (yqp[p] >> 16) | (yqp[p+1] << 16);
        yqp[15] = (yqp[15] >> 16);
        #pragma unroll
        for (int k=0;k<8;++k){
          float a = 0.f;
          #pragma unroll
          for (int p=0;p<16;++p)
            a = fdot2f(wyb[(size_t)(16*k+p)*256 + j], yqp[p], a);
          u_part[k] = a;
        }
      }
      for (int i=0;i<N_IDLE;++i) __builtin_amdgcn_s_sleep(SLP_IDLE);
    }

    // epilogue: y[L-1]
    if (X == 0){
      u32 rec[8];
      u32* base = hb + (size_t)3*WIDTH;
      const u32 tag = (u32)(L_SEQ-1);
      for(;;){
        #pragma unroll
        for (int k=0;k<8;++k) rec[k] = aload(base + 256*k + j);
        bool ok = true;
        #pragma unroll
        for (int k=0;k<8;++k) ok &= ((rec[k] >> 16) == tag);
        if (ok) break;
        __builtin_amdgcn_s_sleep(SLP_FAIL);
      }
      float yp = 0.f;
      #pragma unroll
      for (int k=0;k<8;++k) yp += w5f[k] * h2f(rec[k]);
      #pragma unroll
      for (int d=1; d<64; d<<=1) yp += __shfl_xor(yp, d);
      if (lw == 0) redp[w] = yp;
      __syncthreads();
      if (j == 0) out[L_SEQ-1] = fmaxf(redp[0]+redp[1]+redp[2]+redp[3] + b5v, 0.f);
    }
  }
}

extern "C" void kernel_launch(void* const* d_in, const int* in_sizes, int n_in,
                              void* d_out, int out_size, void* d_ws, size_t ws_size,
                              hipStream_t stream) {
  (void)in_sizes; (void)n_in; (void)out_size; (void)ws_size;
  const int*   x  = (const int*)  d_in[0];
  const float* W0 = (const float*)d_in[1];
  const float* b0 = (const float*)d_in[2];
  const float* W1 = (const float*)d_in[3];
  const float* b1 = (const float*)d_in[4];
  const float* W2 = (const float*)d_in[5];
  const float* b2 = (const float*)d_in[6];
  const float* W3 = (const float*)d_in[7];
  const float* b3 = (const float*)d_in[8];
  const float* W4 = (const float*)d_in[9];
  const float* b4 = (const float*)d_in[10];
  const float* W5 = (const float*)d_in[11];
  const float* b5 = (const float*)d_in[12];
  float* out = (float*)d_out;
  char*  ws  = (char*)d_ws;

  // ws layout (16B-aligned), total ~47.9 MB
  constexpr size_t OFF_WP  = 0;                       // 4*2048*256*16 = 33,554,432
  constexpr size_t OFF_C0  = 33554432;                // 2048*256*16   =  8,388,608
  constexpr size_t OFF_W0T = 41943040;                // 704*2048*4    =  5,767,168
  constexpr size_t OFF_WY  = 47710208;                // 128*256*4     =    131,072
  constexpr size_t OFF_HB  = 47841280;                // 4*2048*4      =     32,768

  uint4* Wp  = (uint4*)(ws + OFF_WP);
  uint4* c0p = (uint4*)(ws + OFF_C0);
  float* W0T = (float*)(ws + OFF_W0T);
  u32*   wyb = (u32*)  (ws + OFF_WY);
  u32*   hb  = (u32*)  (ws + OFF_HB);

  k_wt   <<<5632, 256, 0, stream>>>(W0, W0T);
  k_wc   <<<8192, 256, 0, stream>>>(W1, W2, W3, W4, Wp);
  k_c0   <<<2048, 256, 0, stream>>>(x, W0T, b0, c0p);
  k_wy   <<<128,  256, 0, stream>>>(W0, wyb);
  k_reset<<<32,   256, 0, stream>>>(hb);
  k_main <<<NB,   256, 0, stream>>>(W0, b1, b2, b3, b4, W5, b5,
                                    Wp, c0p, wyb, hb, out);
}